// Round 11
// baseline (390.763 us; speedup 1.0000x reference)
//
#include <hip/hip_runtime.h>
#include <hip/hip_bf16.h>

// Problem: x[2,2048,2048] fp32; w_qkv[6144,2048]; b_qkv[6144]; w_out[2048,2048]; b_out[2048]
// out[2,2048,2048] fp32.  H=2048, NH=16, HD=128, S=2048, B=2, M=B*S=4096.

typedef __bf16 bf16x8 __attribute__((ext_vector_type(8)));
typedef float f32x4 __attribute__((ext_vector_type(4)));
typedef unsigned short ushort8_t __attribute__((ext_vector_type(8)));
typedef unsigned short ushort4_t __attribute__((ext_vector_type(4)));

__device__ __forceinline__ unsigned short f2bf(float f) {
  unsigned int u = __float_as_uint(f);
  u += 0x7fffu + ((u >> 16) & 1u);   // RNE
  return (unsigned short)(u >> 16);
}

__device__ __forceinline__ unsigned int pk2bf(float lo, float hi) {
  unsigned int a = (__float_as_uint(lo) + 0x8000u) >> 16;
  unsigned int b = (__float_as_uint(hi) + 0x8000u) & 0xffff0000u;
  return a | b;
}

__device__ __forceinline__ float fexp2(float x) {
#if __has_builtin(__builtin_amdgcn_exp2f)
  return __builtin_amdgcn_exp2f(x);
#else
  return exp2f(x);
#endif
}

__device__ __forceinline__ f32x4 mfma16(bf16x8 a, bf16x8 b, f32x4 c) {
  return __builtin_amdgcn_mfma_f32_16x16x32_bf16(a, b, c, 0, 0, 0);
}

__device__ __forceinline__ void gload_lds16(const void* g, void* lds) {
  __builtin_amdgcn_global_load_lds(
      (const __attribute__((address_space(1))) unsigned int*)g,
      (__attribute__((address_space(3))) unsigned int*)lds, 16, 0, 0);
}

// ---------------- fused fp32 -> bf16 convert, all three tensors, one dispatch ----
__global__ __launch_bounds__(256) void cvt_all_k(const float* __restrict__ x,
                                                 const float* __restrict__ wqkv,
                                                 const float* __restrict__ wout,
                                                 unsigned short* __restrict__ xb,
                                                 unsigned short* __restrict__ wqkvb,
                                                 unsigned short* __restrict__ woutb) {
  int i = (blockIdx.x * 256 + threadIdx.x) * 8;
  const float* in;
  unsigned short* out;
  if (i < 8388608) {
    in = x + i; out = xb + i;
  } else if (i < 20971520) {
    in = wqkv + (i - 8388608); out = wqkvb + (i - 8388608);
  } else {
    in = wout + (i - 20971520); out = woutb + (i - 20971520);
  }
  float4 a = *(const float4*)(in);
  float4 b = *(const float4*)(in + 4);
  ushort8_t o;
  o[0] = f2bf(a.x); o[1] = f2bf(a.y); o[2] = f2bf(a.z); o[3] = f2bf(a.w);
  o[4] = f2bf(b.x); o[5] = f2bf(b.y); o[6] = f2bf(b.z); o[7] = f2bf(b.w);
  *(ushort8_t*)(out) = o;
}

// ---------------- merged projection GEMM: C = xb * wqkvb^T + b_qkv, N=6144 -------
// grid (48, 32): n0 < 4096 -> Q,K rows of qkvb (bf16, stride 6144);
//                n0 >= 4096 -> V out-features, written transposed to vT[bh][d][s].
// Merging the former QK (32x32) and V (16x32) dispatches removes one launch
// boundary and lets the QK tail overlap V blocks (6 blocks/CU for the whole run).
__global__ __launch_bounds__(256) void gemm_proj(const unsigned short* __restrict__ A,
                                                 const unsigned short* __restrict__ B,
                                                 const float* __restrict__ bias,
                                                 unsigned short* __restrict__ qkvb,
                                                 unsigned short* __restrict__ vT) {
  const int K = 2048;
  __shared__ __attribute__((aligned(16))) unsigned short As[128 * 64];
  __shared__ __attribute__((aligned(16))) unsigned short Bs[128 * 64];
  const int tid = threadIdx.x;
  const int lane = tid & 63;
  const int wv = tid >> 6;
  const int wm = wv >> 1, wn = wv & 1;
  const int lr = lane & 15, lg = lane >> 4;
  const int m0 = blockIdx.y * 128, n0 = blockIdx.x * 128;

  f32x4 acc[4][4];
#pragma unroll
  for (int i = 0; i < 4; ++i)
#pragma unroll
    for (int j = 0; j < 4; ++j) acc[i][j] = (f32x4){0.f, 0.f, 0.f, 0.f};

  for (int kt = 0; kt < K; kt += 64) {
    __syncthreads();
#pragma unroll
    for (int i = 0; i < 4; ++i) {
      int c = i * 256 + tid;
      int r = c >> 3;
      int lc = (c & 7) ^ (r & 7);
      gload_lds16(A + (size_t)(m0 + r) * K + kt + lc * 8, &As[c * 8]);
      gload_lds16(B + (size_t)(n0 + r) * K + kt + lc * 8, &Bs[c * 8]);
    }
    __syncthreads();
#pragma unroll
    for (int kk = 0; kk < 64; kk += 32) {
      bf16x8 af[4], bf[4];
#pragma unroll
      for (int i = 0; i < 4; ++i) {
        int pcA = ((kk >> 3) + lg) ^ (lr & 7);
        af[i] = *(const bf16x8*)&As[(wm * 64 + i * 16 + lr) * 64 + pcA * 8];
        bf[i] = *(const bf16x8*)&Bs[(wn * 64 + i * 16 + lr) * 64 + pcA * 8];
      }
#pragma unroll
      for (int i = 0; i < 4; ++i)
#pragma unroll
        for (int j = 0; j < 4; ++j) acc[i][j] = mfma16(af[i], bf[j], acc[i][j]);
    }
  }

  const bool vmode = (n0 >= 4096);
#pragma unroll
  for (int j = 0; j < 4; ++j) {
    int n = n0 + wn * 64 + j * 16 + lr;
    float bv = bias[n];
#pragma unroll
    for (int i = 0; i < 4; ++i) {
      int mbase = m0 + wm * 64 + i * 16 + lg * 4;
      if (vmode) {
        int nv = n - 4096;
        int hh = nv >> 7, dd = nv & 127;
        int b = mbase >> 11, s = mbase & 2047;
        ushort4_t o4;
#pragma unroll
        for (int r = 0; r < 4; ++r) o4[r] = f2bf(acc[i][j][r] + bv);
        *(ushort4_t*)&vT[((size_t)((b * 16 + hh) * 128 + dd)) * 2048 + s] = o4;
      } else {
#pragma unroll
        for (int r = 0; r < 4; ++r)
          qkvb[(size_t)(mbase + r) * 6144 + n] = f2bf(acc[i][j][r] + bv);
      }
    }
  }
}

// ---------------- NT bf16 GEMM (128x128, m97 structure) — out-projection --------
__global__ __launch_bounds__(256) void gemm_nt0(const unsigned short* __restrict__ A,
                                                const unsigned short* __restrict__ B,
                                                const float* __restrict__ bias,
                                                float* __restrict__ Cout,
                                                int Ns, int K) {
  __shared__ __attribute__((aligned(16))) unsigned short As[128 * 64];
  __shared__ __attribute__((aligned(16))) unsigned short Bs[128 * 64];
  const int tid = threadIdx.x;
  const int lane = tid & 63;
  const int wv = tid >> 6;
  const int wm = wv >> 1, wn = wv & 1;
  const int lr = lane & 15, lg = lane >> 4;
  const int m0 = blockIdx.y * 128, n0 = blockIdx.x * 128;

  f32x4 acc[4][4];
#pragma unroll
  for (int i = 0; i < 4; ++i)
#pragma unroll
    for (int j = 0; j < 4; ++j) acc[i][j] = (f32x4){0.f, 0.f, 0.f, 0.f};

  for (int kt = 0; kt < K; kt += 64) {
    __syncthreads();
#pragma unroll
    for (int i = 0; i < 4; ++i) {
      int c = i * 256 + tid;
      int r = c >> 3;
      int lc = (c & 7) ^ (r & 7);
      gload_lds16(A + (size_t)(m0 + r) * K + kt + lc * 8, &As[c * 8]);
      gload_lds16(B + (size_t)(n0 + r) * K + kt + lc * 8, &Bs[c * 8]);
    }
    __syncthreads();
#pragma unroll
    for (int kk = 0; kk < 64; kk += 32) {
      bf16x8 af[4], bf[4];
#pragma unroll
      for (int i = 0; i < 4; ++i) {
        int pcA = ((kk >> 3) + lg) ^ (lr & 7);
        af[i] = *(const bf16x8*)&As[(wm * 64 + i * 16 + lr) * 64 + pcA * 8];
        bf[i] = *(const bf16x8*)&Bs[(wn * 64 + i * 16 + lr) * 64 + pcA * 8];
      }
#pragma unroll
      for (int i = 0; i < 4; ++i)
#pragma unroll
        for (int j = 0; j < 4; ++j) acc[i][j] = mfma16(af[i], bf[j], acc[i][j]);
    }
  }

#pragma unroll
  for (int j = 0; j < 4; ++j) {
    int n = n0 + wn * 64 + j * 16 + lr;
    float bv = bias[n];
#pragma unroll
    for (int i = 0; i < 4; ++i) {
      int mbase = m0 + wm * 64 + i * 16 + lg * 4;
#pragma unroll
      for (int r = 0; r < 4; ++r)
        Cout[(size_t)(mbase + r) * Ns + n] = acc[i][j][r] + bv;
    }
  }
}

// stage K tile [64][128] swz16 for kv-tile t (4 gload_lds/thread)
__device__ __forceinline__ void stage_K(const unsigned short* __restrict__ qkv,
                                        int b, int h, int t, int tid,
                                        unsigned short* KsB) {
  const int krow = b * 2048 + t * 64;
#pragma unroll
  for (int i = 0; i < 4; ++i) {
    int c = i * 256 + tid;
    int r = c >> 4;
    int lc = (c & 15) ^ (r & 15);
    gload_lds16(qkv + (size_t)(krow + r) * 6144 + 2048 + h * 128 + lc * 8, &KsB[c * 8]);
  }
}

// stage Vt tile [128][64] swz8 for kv-tile t (4 gload_lds/thread)
__device__ __forceinline__ void stage_V(const unsigned short* __restrict__ vbase,
                                        int t, int tid, unsigned short* VtB) {
  const int s0k = t * 64;
#pragma unroll
  for (int i = 0; i < 4; ++i) {
    int c = i * 256 + tid;
    int r = c >> 3;
    int lc = (c & 7) ^ (r & 7);
    gload_lds16(vbase + (size_t)r * 2048 + s0k + lc * 8, &VtB[c * 8]);
  }
}

// ---------------- flash attention, staged dbuf + T15 cross-tile interleave ------
// (R10 winner: PV(i) interleaved with QK(i+1), one barrier/iter, dbuf slots on
// opposite phases; ~85 µs. Unchanged.)
__global__ __launch_bounds__(256, 2) void flash_attn(const unsigned short* __restrict__ qkv,
                                                     const unsigned short* __restrict__ vT,
                                                     unsigned short* __restrict__ attnb) {
  __shared__ __attribute__((aligned(16))) unsigned short Ks0[64 * 128];
  __shared__ __attribute__((aligned(16))) unsigned short Ks1[64 * 128];
  __shared__ __attribute__((aligned(16))) unsigned short Vt0[128 * 64];
  __shared__ __attribute__((aligned(16))) unsigned short Vt1[128 * 64];

  const int tid = threadIdx.x;
  const int lane = tid & 63;
  const int w = tid >> 6;
  const int bh = blockIdx.y;
  const int b = bh >> 4, h = bh & 15;
  const int q0 = blockIdx.x * 128;
  const int lr = lane & 15, lg = lane >> 4;
  const float cs = 0.08838834764831845f * 1.44269504088896340f;

  const unsigned short* vbase = vT + (size_t)bh * 128 * 2048;

  bf16x8 qf[2][4];
#pragma unroll
  for (int g = 0; g < 2; ++g) {
    int m = b * 2048 + q0 + w * 32 + g * 16 + lr;
    const unsigned short* qrow = qkv + (size_t)m * 6144 + h * 128;
#pragma unroll
    for (int kb = 0; kb < 4; ++kb) qf[g][kb] = *(const bf16x8*)(qrow + kb * 32 + lg * 8);
  }

  float l_i[2] = {0.f, 0.f};
  f32x4 O[2][8];
#pragma unroll
  for (int g = 0; g < 2; ++g)
#pragma unroll
    for (int nb = 0; nb < 8; ++nb) O[g][nb] = (f32x4){0.f, 0.f, 0.f, 0.f};

  stage_K(qkv, b, h, 0, tid, Ks0);
  stage_V(vbase, 0, tid, Vt0);
  stage_K(qkv, b, h, 1, tid, Ks1);
  __syncthreads();

  unsigned int pk[2][4][2];
  {
    f32x4 sc[2][4];
#pragma unroll
    for (int g = 0; g < 2; ++g)
#pragma unroll
      for (int cb = 0; cb < 4; ++cb) sc[g][cb] = (f32x4){0.f, 0.f, 0.f, 0.f};
    __builtin_amdgcn_s_setprio(1);
#pragma unroll
    for (int cb = 0; cb < 4; ++cb) {
#pragma unroll
      for (int kb = 0; kb < 4; ++kb) {
        int pc = (kb * 4 + lg) ^ lr;
        bf16x8 kf = *(const bf16x8*)&Ks0[(cb * 16 + lr) * 128 + pc * 8];
        sc[0][cb] = mfma16(kf, qf[0][kb], sc[0][cb]);
        sc[1][cb] = mfma16(kf, qf[1][kb], sc[1][cb]);
      }
    }
    __builtin_amdgcn_s_setprio(0);
#pragma unroll
    for (int g = 0; g < 2; ++g) {
      float rs = 0.f;
#pragma unroll
      for (int cb = 0; cb < 4; ++cb) {
        float p0 = fexp2(sc[g][cb][0] * cs);
        float p1 = fexp2(sc[g][cb][1] * cs);
        float p2 = fexp2(sc[g][cb][2] * cs);
        float p3 = fexp2(sc[g][cb][3] * cs);
        rs += (p0 + p1) + (p2 + p3);
        pk[g][cb][0] = pk2bf(p0, p1);
        pk[g][cb][1] = pk2bf(p2, p3);
      }
      rs += __shfl_xor(rs, 16, 64);
      rs += __shfl_xor(rs, 32, 64);
      l_i[g] += rs;
    }
  }

  unsigned short* Kread = Ks1;  unsigned short* Kwrite = Ks0;
  unsigned short* Vread = Vt0;  unsigned short* Vwrite = Vt1;

  for (int i = 0; i < 32; ++i) {
    __syncthreads();
    if (i + 2 < 32) stage_K(qkv, b, h, i + 2, tid, Kwrite);
    if (i + 1 < 32) stage_V(vbase, i + 1, tid, Vwrite);
    const bool nx = (i + 1 < 32);

    f32x4 sc[2][4];
    if (nx) {
#pragma unroll
      for (int g = 0; g < 2; ++g)
#pragma unroll
        for (int cb = 0; cb < 4; ++cb) sc[g][cb] = (f32x4){0.f, 0.f, 0.f, 0.f};
    }

    if (nx) {
      __builtin_amdgcn_s_setprio(1);
#pragma unroll
      for (int cb = 0; cb < 2; ++cb) {
#pragma unroll
        for (int kb = 0; kb < 4; ++kb) {
          int pc = (kb * 4 + lg) ^ lr;
          bf16x8 kf = *(const bf16x8*)&Kread[(cb * 16 + lr) * 128 + pc * 8];
          sc[0][cb] = mfma16(kf, qf[0][kb], sc[0][cb]);
          sc[1][cb] = mfma16(kf, qf[1][kb], sc[1][cb]);
        }
      }
      __builtin_amdgcn_s_setprio(0);
    }

    {
      bf16x8 pf[2];
#pragma unroll
      for (int g = 0; g < 2; ++g) {
        unsigned int a0 = pk[g][0][0];
        unsigned int b0 = pk[g][1][0];
        unsigned int a1 = pk[g][0][1];
        unsigned int b1 = pk[g][1][1];
        asm("v_permlane32_swap_b32 %0, %1" : "+v"(a0), "+v"(b0));
        asm("v_permlane16_swap_b32 %0, %1" : "+v"(a0), "+v"(b0));
        asm("v_permlane32_swap_b32 %0, %1" : "+v"(a1), "+v"(b1));
        asm("v_permlane16_swap_b32 %0, %1" : "+v"(a1), "+v"(b1));
        uint4 u;
        u.x = a0; u.y = a1; u.z = b0; u.w = b1;
        pf[g] = *(bf16x8*)&u;
      }
      __builtin_amdgcn_s_setprio(1);
#pragma unroll
      for (int nb = 0; nb < 8; ++nb) {
        int pc = lg ^ (lr & 7);
        bf16x8 vtf = *(const bf16x8*)&Vread[(nb * 16 + lr) * 64 + pc * 8];
        O[0][nb] = mfma16(vtf, pf[0], O[0][nb]);
        O[1][nb] = mfma16(vtf, pf[1], O[1][nb]);
      }
      __builtin_amdgcn_s_setprio(0);
    }

    if (nx) {
      __builtin_amdgcn_s_setprio(1);
#pragma unroll
      for (int cb = 2; cb < 4; ++cb) {
#pragma unroll
        for (int kb = 0; kb < 4; ++kb) {
          int pc = (kb * 4 + lg) ^ lr;
          bf16x8 kf = *(const bf16x8*)&Kread[(cb * 16 + lr) * 128 + pc * 8];
          sc[0][cb] = mfma16(kf, qf[0][kb], sc[0][cb]);
          sc[1][cb] = mfma16(kf, qf[1][kb], sc[1][cb]);
        }
      }
      __builtin_amdgcn_s_setprio(0);
    }

    {
      bf16x8 pf[2];
#pragma unroll
      for (int g = 0; g < 2; ++g) {
        unsigned int a0 = pk[g][2][0];
        unsigned int b0 = pk[g][3][0];
        unsigned int a1 = pk[g][2][1];
        unsigned int b1 = pk[g][3][1];
        asm("v_permlane32_swap_b32 %0, %1" : "+v"(a0), "+v"(b0));
        asm("v_permlane16_swap_b32 %0, %1" : "+v"(a0), "+v"(b0));
        asm("v_permlane32_swap_b32 %0, %1" : "+v"(a1), "+v"(b1));
        asm("v_permlane16_swap_b32 %0, %1" : "+v"(a1), "+v"(b1));
        uint4 u;
        u.x = a0; u.y = a1; u.z = b0; u.w = b1;
        pf[g] = *(bf16x8*)&u;
      }
      __builtin_amdgcn_s_setprio(1);
#pragma unroll
      for (int nb = 0; nb < 8; ++nb) {
        int pc = (4 + lg) ^ (lr & 7);
        bf16x8 vtf = *(const bf16x8*)&Vread[(nb * 16 + lr) * 64 + pc * 8];
        O[0][nb] = mfma16(vtf, pf[0], O[0][nb]);
        O[1][nb] = mfma16(vtf, pf[1], O[1][nb]);
      }
      __builtin_amdgcn_s_setprio(0);
    }

    if (nx) {
#pragma unroll
      for (int g = 0; g < 2; ++g) {
        float rs = 0.f;
#pragma unroll
        for (int cb = 0; cb < 4; ++cb) {
          float p0 = fexp2(sc[g][cb][0] * cs);
          float p1 = fexp2(sc[g][cb][1] * cs);
          float p2 = fexp2(sc[g][cb][2] * cs);
          float p3 = fexp2(sc[g][cb][3] * cs);
          rs += (p0 + p1) + (p2 + p3);
          pk[g][cb][0] = pk2bf(p0, p1);
          pk[g][cb][1] = pk2bf(p2, p3);
        }
        rs += __shfl_xor(rs, 16, 64);
        rs += __shfl_xor(rs, 32, 64);
        l_i[g] += rs;
      }
    }

    unsigned short* tk = Kread; Kread = Kwrite; Kwrite = tk;
    unsigned short* tv = Vread; Vread = Vwrite; Vwrite = tv;
  }

#pragma unroll
  for (int g = 0; g < 2; ++g) {
    int m = b * 2048 + q0 + w * 32 + g * 16 + lr;
    float inv = 1.0f / l_i[g];
    unsigned short* orow = attnb + (size_t)m * 2048 + h * 128;
#pragma unroll
    for (int nb = 0; nb < 8; ++nb) {
      ushort4_t o4;
#pragma unroll
      for (int r = 0; r < 4; ++r) o4[r] = f2bf(O[g][nb][r] * inv);
      *(ushort4_t*)&orow[nb * 16 + lg * 4] = o4;
    }
  }
}

extern "C" void kernel_launch(void* const* d_in, const int* in_sizes, int n_in,
                              void* d_out, int out_size, void* d_ws, size_t ws_size,
                              hipStream_t stream) {
  const float* x = (const float*)d_in[0];       // 2*2048*2048
  const float* w_qkv = (const float*)d_in[1];   // 6144*2048
  const float* b_qkv = (const float*)d_in[2];   // 6144
  const float* w_out = (const float*)d_in[3];   // 2048*2048
  const float* b_out = (const float*)d_in[4];   // 2048
  float* out = (float*)d_out;                   // 2*2048*2048

  char* ws = (char*)d_ws;
  unsigned short* xb = (unsigned short*)ws;             // 16 MB region A
  unsigned short* attnb = xb;                           //   reused after proj GEMM
  unsigned short* wqkvb = (unsigned short*)(ws + (16u << 20));  // 24 MB region B
  unsigned short* qkvb = (unsigned short*)(ws + (40u << 20));   // 48 MB region C (Q,K)
  unsigned short* vT = (unsigned short*)(ws + (88u << 20));     // 16 MB region D
  unsigned short* woutb = (unsigned short*)(ws + (104ull << 20)); // 8 MB region E

  // all three converts in one dispatch
  cvt_all_k<<<25165824 / 2048, 256, 0, stream>>>(x, w_qkv, w_out, xb, wqkvb, woutb);

  // merged QKV projection: one dispatch, grid 48x32 (Q,K -> qkvb; V -> vT)
  gemm_proj<<<dim3(48, 32), 256, 0, stream>>>(xb, wqkvb, b_qkv, qkvb, vT);

  flash_attn<<<dim3(16, 32), 256, 0, stream>>>(qkvb, vT, attnb);

  gemm_nt0<<<dim3(16, 32), 256, 0, stream>>>(attnb, woutb, b_out, out, 2048, 2048);
}